// Round 1
// 1207.814 us; speedup vs baseline: 1.0876x; 1.0876x over previous
//
#include <hip/hip_runtime.h>
#include <hip/hip_bf16.h>
#include <cstdint>
#include <cstddef>

#define LN_EPS 1e-5f

typedef __attribute__((ext_vector_type(8))) short short8;   // 8 bf16 = 4 VGPRs
typedef __attribute__((ext_vector_type(4))) float f32x4;    // MFMA accumulator

static __device__ __forceinline__ unsigned short f2bf(float x) {
    union { float f; unsigned u; } v; v.f = x;
    unsigned r = v.u + 0x7FFFu + ((v.u >> 16) & 1u);   // round-to-nearest-even
    return (unsigned short)(r >> 16);
}
static __device__ __forceinline__ float bf2f(unsigned short b) {
    union { unsigned u; float f; } v; v.u = ((unsigned)b) << 16;
    return v.f;
}
// two fp32 -> packed bf16x2 (compiler emits v_cvt_pk_bf16_f32 on gfx950)
static __device__ __forceinline__ unsigned cvt2(float lo, float hi) {
    float2 p; p.x = lo; p.y = hi;
    __hip_bfloat162 h = __float22bfloat162_rn(p);
    unsigned u; __builtin_memcpy(&u, &h, 4); return u;
}

// ---------------- weight prep: fp32 -> bf16, fold zero_time_feat into q-bias ----
__global__ void prep_kernel(const float* __restrict__ Wq, const float* __restrict__ bq,
                            const float* __restrict__ Wk, const float* __restrict__ Wv,
                            const float* __restrict__ Wout, const float* __restrict__ tb,
                            unsigned short* __restrict__ wkv, unsigned short* __restrict__ wq,
                            unsigned short* __restrict__ wout, float* __restrict__ qbias) {
    int tid = blockIdx.x * blockDim.x + threadIdx.x;
    if (tid < 256 * 384) {           // WKV: rows 0..127 = Wk, 128..255 = Wv  [256][384]
        int o = tid / 384, k = tid % 384;
        float w = (o < 128) ? Wk[o * 384 + k] : Wv[(o - 128) * 384 + k];
        wkv[tid] = f2bf(w);
    }
    if (tid < 128 * 128) {           // Wq first 128 input cols  [128][128]
        int o = tid / 128, i = tid % 128;
        wq[tid] = f2bf(Wq[o * 256 + i]);
    }
    if (tid < 128 * 256) {           // Wout  [128][256]
        wout[tid] = f2bf(Wout[tid]);
    }
    if (tid < 128) {                 // qbias[o] = bq[o] + sum_t cos(tb[t]) * Wq[o][128+t]
        float s = bq[tid];
        for (int t = 0; t < 128; ++t) s += cosf(tb[t]) * Wq[tid * 256 + 128 + t];
        qbias[tid] = s;
    }
}

// ---------------- fused K/V GEMM v2 --------------------------------------------
// tile 128 edges x 256 outputs, 512 thr (8 waves, 2M x 4N), K=384.
// K-chunks 0..3 (h,f cols): fp32 staged via global_load_lds, double-buffered,
// XOR-swizzled ((row&7)<<5) against the stride-256B bank conflict.
// K-chunks 4..5 (time feat): computed per-lane in registers, no LDS.
// MFMA operands swapped (W = A, edges = B) so each lane owns 4 consecutive
// output channels -> packed 8B stores in the epilogue.
__launch_bounds__(512, 4)
__global__ void gemm_kv_kernel(const float* __restrict__ h, const float* __restrict__ f,
                               const float* __restrict__ dt, const float* __restrict__ freq,
                               const float* __restrict__ tb,
                               const unsigned short* __restrict__ wkv,
                               const float* __restrict__ bk, const float* __restrict__ bv,
                               unsigned short* __restrict__ Kb, unsigned short* __restrict__ Vb,
                               int Nd, int E) {
    __shared__ __align__(1024) float ldsA[2][8192];      // 2 x 32KB: [128 rows][64 f32]
    const int tid = threadIdx.x;
    const int w  = tid >> 6, l = tid & 63, ln = l & 15, lq = l >> 4;
    const int wm = w >> 2, wn = w & 3;                   // wave grid 2M x 4N
    const long e_base = (long)blockIdx.x * 128;

    auto stage = [&](int c, int buf) {                   // one 64-col fp32 K-chunk
        #pragma unroll
        for (int i = 0; i < 4; ++i) {
            int inst = w * 4 + i;                        // 32 x 1KB instrs across 8 waves
            int a    = inst * 1024 + l * 16;             // linear byte offset in 32KB tile
            int row  = a >> 8;
            int colb = (a & 255) ^ ((row & 7) << 5);     // inverse-swizzled source col
            long er  = e_base + row; if (er >= E) er = E - 1;
            const float* g = (c < 2) ? h + ((long)Nd + er) * 128 + c * 64 + (colb >> 2)
                                     : f + er * 128 + (c - 2) * 64 + (colb >> 2);
            __builtin_amdgcn_global_load_lds(
                (const __attribute__((address_space(1))) void*)g,
                (__attribute__((address_space(3))) void*)&ldsA[buf][inst * 256],
                16, 0, 0);
        }
    };

    stage(0, 0);
    f32x4 acc[4][4] = {};
    __syncthreads();

    int buf = 0;
    #pragma unroll
    for (int c = 0; c < 4; ++c) {
        // weight frags first (older than prefetch -> counted vmcnt wait)
        short8 wfr[2][4];
        #pragma unroll
        for (int ksl = 0; ksl < 2; ++ksl)
            #pragma unroll
            for (int nt = 0; nt < 4; ++nt) {
                int o = wn * 64 + nt * 16 + ln;
                wfr[ksl][nt] = *(const short8*)(wkv + o * 384 + c * 64 + ksl * 32 + lq * 8);
            }
        if (c < 3) stage(c + 1, buf ^ 1);                // prefetch next chunk
        #pragma unroll
        for (int ksl = 0; ksl < 2; ++ksl) {
            #pragma unroll
            for (int mt = 0; mt < 4; ++mt) {
                int row = wm * 64 + mt * 16 + ln;
                int swz = ((ksl * 32 + lq * 8) << 2) ^ ((row & 7) << 5);
                const float* p = &ldsA[buf][row * 64 + (swz >> 2)];
                float4 x0 = *(const float4*)p;
                float4 x1 = *(const float4*)(p + 4);
                union { short8 s; unsigned u[4]; } v;
                v.u[0] = cvt2(x0.x, x0.y); v.u[1] = cvt2(x0.z, x0.w);
                v.u[2] = cvt2(x1.x, x1.y); v.u[3] = cvt2(x1.z, x1.w);
                #pragma unroll
                for (int nt = 0; nt < 4; ++nt)
                    acc[mt][nt] = __builtin_amdgcn_mfma_f32_16x16x32_bf16(
                        wfr[ksl][nt], v.s, acc[mt][nt], 0, 0, 0);
            }
        }
        __syncthreads();
        buf ^= 1;
    }

    // ---- time-feature K-chunks (t = 0..127), fully in-register ----
    float dval[4];
    #pragma unroll
    for (int mt = 0; mt < 4; ++mt) {
        long e = e_base + wm * 64 + mt * 16 + ln;
        if (e >= E) e = E - 1;
        dval[mt] = dt[e];
    }
    #pragma unroll
    for (int ks = 0; ks < 4; ++ks) {
        int t0 = ks * 32 + lq * 8;
        short8 wfr[4];
        #pragma unroll
        for (int nt = 0; nt < 4; ++nt) {
            int o = wn * 64 + nt * 16 + ln;
            wfr[nt] = *(const short8*)(wkv + o * 384 + 256 + ks * 32 + lq * 8);
        }
        float4 f0 = *(const float4*)(freq + t0);
        float4 f1 = *(const float4*)(freq + t0 + 4);
        float4 b0 = *(const float4*)(tb + t0);
        float4 b1 = *(const float4*)(tb + t0 + 4);
        #pragma unroll
        for (int mt = 0; mt < 4; ++mt) {
            float d = dval[mt];
            union { short8 s; unsigned u[4]; } v;
            v.u[0] = cvt2(__cosf(fmaf(d, f0.x, b0.x)), __cosf(fmaf(d, f0.y, b0.y)));
            v.u[1] = cvt2(__cosf(fmaf(d, f0.z, b0.z)), __cosf(fmaf(d, f0.w, b0.w)));
            v.u[2] = cvt2(__cosf(fmaf(d, f1.x, b1.x)), __cosf(fmaf(d, f1.y, b1.y)));
            v.u[3] = cvt2(__cosf(fmaf(d, f1.z, b1.z)), __cosf(fmaf(d, f1.w, b1.w)));
            #pragma unroll
            for (int nt = 0; nt < 4; ++nt)
                acc[mt][nt] = __builtin_amdgcn_mfma_f32_16x16x32_bf16(
                    wfr[nt], v.s, acc[mt][nt], 0, 0, 0);
        }
    }

    // ---- epilogue: D[o][e] layout -> 4 consecutive channels per lane, 8B stores
    #pragma unroll
    for (int nt = 0; nt < 4; ++nt) {
        int o0 = wn * 64 + nt * 16 + lq * 4;             // K/V split uniform per nt tile
        const float* bsrc = (o0 < 128) ? (bk + o0) : (bv + (o0 - 128));
        float4 b4 = *(const float4*)bsrc;
        #pragma unroll
        for (int mt = 0; mt < 4; ++mt) {
            long e = e_base + wm * 64 + mt * 16 + ln;
            if (e >= E) continue;
            f32x4 a = acc[mt][nt];
            uint2 u;
            u.x = cvt2(a[0] + b4.x, a[1] + b4.y);
            u.y = cvt2(a[2] + b4.z, a[3] + b4.w);
            unsigned short* dst = (o0 < 128) ? (Kb + e * 128 + o0)
                                             : (Vb + e * 128 + (o0 - 128));
            *(uint2*)dst = u;
        }
    }
}

// ---------------- node GEMM: out[M][128] = [src0 | src1] @ W^T + bias (opt relu) ---
// ksteps = Kd/32 (4 for Q, 8 for Wout). block 256 thr, tile 64 rows x 128 cols.
// MFMA operands swapped -> float4 epilogue stores.
__launch_bounds__(256)
__global__ void gemm_node_kernel(const float* __restrict__ src0, const float* __restrict__ src1,
                                 const unsigned short* __restrict__ W, const float* __restrict__ bias,
                                 float* __restrict__ out, int M, int ksteps, int do_relu) {
    __shared__ unsigned short ldsA[4 * 8 * 64 * 8];      // up to Kd=256
    const int tid = threadIdx.x;
    const long m_base = (long)blockIdx.x * 64;
    const int Kd = ksteps * 32;
    const int g4 = Kd / 4;

    for (int g = tid; g < 64 * g4; g += 256) {
        int r  = g / g4;
        int c4 = (g % g4) * 4;
        long m = m_base + r; if (m >= M) m = M - 1;
        float4 x = (c4 < 128) ? *(const float4*)(src0 + m * 128 + c4)
                              : *(const float4*)(src1 + m * 128 + (c4 - 128));
        int lane = (r & 15) | (((c4 >> 3) & 3) << 4);
        int base = (((r >> 4) * ksteps + (c4 >> 5)) * 64 + lane) * 8 + (c4 & 7);
        *(unsigned*)&ldsA[base]     = cvt2(x.x, x.y);
        *(unsigned*)&ldsA[base + 2] = cvt2(x.z, x.w);
    }
    __syncthreads();

    const int w = tid >> 6, l = tid & 63, ln = l & 15, lq = l >> 4;
    f32x4 acc[4][2] = {};
    for (int ks = 0; ks < ksteps; ++ks) {
        short8 bfr[2];
        #pragma unroll
        for (int nt = 0; nt < 2; ++nt) {
            int row = w * 32 + nt * 16 + ln;             // W stored [N][K] row-major
            bfr[nt] = *(const short8*)(W + row * Kd + ks * 32 + lq * 8);
        }
        #pragma unroll
        for (int mt = 0; mt < 4; ++mt) {
            short8 afr = *(const short8*)&ldsA[((mt * ksteps + ks) * 64 + l) * 8];
            #pragma unroll
            for (int nt = 0; nt < 2; ++nt)
                acc[mt][nt] = __builtin_amdgcn_mfma_f32_16x16x32_bf16(
                    bfr[nt], afr, acc[mt][nt], 0, 0, 0);
        }
    }
    #pragma unroll
    for (int nt = 0; nt < 2; ++nt) {
        int o0 = w * 32 + nt * 16 + lq * 4;
        float4 b4 = *(const float4*)(bias + o0);
        #pragma unroll
        for (int mt = 0; mt < 4; ++mt) {
            long m = m_base + mt * 16 + ln;
            if (m >= M) continue;
            f32x4 a = acc[mt][nt];
            float4 o;
            o.x = a[0] + b4.x; o.y = a[1] + b4.y;
            o.z = a[2] + b4.z; o.w = a[3] + b4.w;
            if (do_relu) {
                o.x = fmaxf(o.x, 0.f); o.y = fmaxf(o.y, 0.f);
                o.z = fmaxf(o.z, 0.f); o.w = fmaxf(o.w, 0.f);
            }
            *(float4*)(out + m * 128 + o0) = o;
        }
    }
}

// ---------------- counting sort of edges by dst ----------------
__global__ void hist_kernel(const int* __restrict__ dst, int* __restrict__ counts, int E) {
    int e = blockIdx.x * blockDim.x + threadIdx.x;
    if (e < E) atomicAdd(&counts[dst[e]], 1);
}

__global__ void scan_kernel(const int* __restrict__ counts, int* __restrict__ offsets,
                            int* __restrict__ cursor, int Nd) {
    __shared__ int sdata[1024];
    int t = threadIdx.x;
    int C = (Nd + 1023) / 1024;
    int b0 = t * C;
    int s = 0;
    for (int i = 0; i < C; ++i) { int idx = b0 + i; if (idx < Nd) s += counts[idx]; }
    sdata[t] = s;
    __syncthreads();
    for (int off = 1; off < 1024; off <<= 1) {
        int v = (t >= off) ? sdata[t - off] : 0;
        __syncthreads();
        sdata[t] += v;
        __syncthreads();
    }
    int run = sdata[t] - s;                              // exclusive prefix of this chunk
    for (int i = 0; i < C; ++i) {
        int idx = b0 + i;
        if (idx < Nd) { offsets[idx] = run; cursor[idx] = run; run += counts[idx]; }
    }
}

__global__ void scatter_kernel(const int* __restrict__ dst, int* __restrict__ cursor,
                               int* __restrict__ order, int E) {
    int e = blockIdx.x * blockDim.x + threadIdx.x;
    if (e < E) { int pos = atomicAdd(&cursor[dst[e]], 1); order[pos] = e; }
}

// ---------------- attention: one block per dst node, online softmax ----------------
__launch_bounds__(128)
__global__ void attn_kernel(const float* __restrict__ Q, const unsigned short* __restrict__ Kb,
                            const unsigned short* __restrict__ Vb,
                            const int* __restrict__ order, const int* __restrict__ offsets,
                            const int* __restrict__ counts, float* __restrict__ agg) {
    const int d = blockIdx.x;
    const int t = threadIdx.x;                           // channel; head = t>>4
    const int beg = offsets[d];
    const int n   = counts[d];
    const float q = Q[(long)d * 128 + t];

    float m = -3.0e38f, lsum = 0.f, acc = 0.f;
    float kk = 0.f, vv = 0.f;
    if (n > 0) {
        int e0 = order[beg];
        kk = bf2f(Kb[(long)e0 * 128 + t]);
        vv = bf2f(Vb[(long)e0 * 128 + t]);
    }
    for (int i = 0; i < n; ++i) {
        float ck = kk, cv = vv;
        if (i + 1 < n) {                                 // prefetch next edge's rows
            int e2 = order[beg + i + 1];
            kk = bf2f(Kb[(long)e2 * 128 + t]);
            vv = bf2f(Vb[(long)e2 * 128 + t]);
        }
        float p = q * ck;
        p += __shfl_xor(p, 1, 16);
        p += __shfl_xor(p, 2, 16);
        p += __shfl_xor(p, 4, 16);
        p += __shfl_xor(p, 8, 16);                       // per-head dot (16 chan)
        float logit = (p > 0.f) ? p : 0.2f * p;          // leaky_relu 0.2
        float mn = fmaxf(m, logit);
        float sc = __expf(m - mn);
        float pe = __expf(logit - mn);
        lsum = lsum * sc + pe;
        acc  = acc * sc + pe * cv;
        m = mn;
    }
    agg[(long)d * 128 + t] = (n > 0) ? acc / lsum : 0.f;
}

// ---------------- layernorm (one wave per row) ----------------
__launch_bounds__(256)
__global__ void ln_kernel(const float* __restrict__ rst, const float* __restrict__ gamma,
                          const float* __restrict__ beta, float* __restrict__ out, int Nd) {
    int wave = threadIdx.x >> 6;
    int lane = threadIdx.x & 63;
    long row = (long)blockIdx.x * 4 + wave;
    if (row >= Nd) return;
    float x0 = rst[row * 128 + lane];
    float x1 = rst[row * 128 + 64 + lane];
    float s = x0 + x1, sq = x0 * x0 + x1 * x1;
    #pragma unroll
    for (int off = 32; off >= 1; off >>= 1) {
        s  += __shfl_xor(s, off, 64);
        sq += __shfl_xor(sq, off, 64);
    }
    float mean = s * (1.f / 128.f);
    float var  = sq * (1.f / 128.f) - mean * mean;
    float rstd = rsqrtf(var + LN_EPS);
    out[row * 128 + lane]      = (x0 - mean) * rstd * gamma[lane]      + beta[lane];
    out[row * 128 + 64 + lane] = (x1 - mean) * rstd * gamma[lane + 64] + beta[lane + 64];
}

// ---------------- host ----------------
extern "C" void kernel_launch(void* const* d_in, const int* in_sizes, int n_in,
                              void* d_out, int out_size, void* d_ws, size_t ws_size,
                              hipStream_t stream) {
    const float* h    = (const float*)d_in[0];
    const float* f    = (const float*)d_in[1];
    const float* dt   = (const float*)d_in[2];
    const int*   dst  = (const int*)d_in[3];
    const float* freq = (const float*)d_in[4];
    const float* tb   = (const float*)d_in[5];
    const float* Wq   = (const float*)d_in[6];
    const float* bq   = (const float*)d_in[7];
    const float* Wk   = (const float*)d_in[8];
    const float* bk   = (const float*)d_in[9];
    const float* Wv   = (const float*)d_in[10];
    const float* bv   = (const float*)d_in[11];
    const float* Wout = (const float*)d_in[12];
    const float* bout = (const float*)d_in[13];
    const float* gamma= (const float*)d_in[14];
    const float* beta = (const float*)d_in[15];

    const int E  = in_sizes[2];
    const int Nd = in_sizes[0] / 128 - E;

    char* ws = (char*)d_ws;
    size_t off = 0;
    auto alloc = [&](size_t b) {
        off = (off + 255) & ~(size_t)255;
        char* p = ws + off; off += b; return p;
    };
    unsigned short* wkv   = (unsigned short*)alloc(256 * 384 * 2);
    unsigned short* wq    = (unsigned short*)alloc(128 * 128 * 2);
    unsigned short* wout  = (unsigned short*)alloc(128 * 256 * 2);
    float*          qbias = (float*)alloc(128 * 4);
    float*          Q     = (float*)alloc((size_t)Nd * 128 * 4);
    unsigned short* Kb    = (unsigned short*)alloc((size_t)E * 128 * 2);
    unsigned short* Vb    = (unsigned short*)alloc((size_t)E * 128 * 2);
    float*          agg   = (float*)alloc((size_t)Nd * 128 * 4);
    int*            counts= (int*)alloc((size_t)Nd * 4);
    int*            offs  = (int*)alloc((size_t)Nd * 4);
    int*            cursor= (int*)alloc((size_t)Nd * 4);
    int*            order = (int*)alloc((size_t)E * 4);
    float*          rst   = (float*)Kb;   // alias: Kb dead after attention

    hipMemsetAsync(counts, 0, (size_t)Nd * 4, stream);
    prep_kernel<<<(256 * 384 + 255) / 256, 256, 0, stream>>>(Wq, bq, Wk, Wv, Wout, tb,
                                                             wkv, wq, wout, qbias);
    hist_kernel<<<(E + 255) / 256, 256, 0, stream>>>(dst, counts, E);
    scan_kernel<<<1, 1024, 0, stream>>>(counts, offs, cursor, Nd);
    scatter_kernel<<<(E + 255) / 256, 256, 0, stream>>>(dst, cursor, order, E);
    gemm_node_kernel<<<(Nd + 63) / 64, 256, 0, stream>>>(h, nullptr, wq, qbias, Q, Nd, 4, 0);
    gemm_kv_kernel<<<(E + 127) / 128, 512, 0, stream>>>(h, f, dt, freq, tb, wkv, bk, bv,
                                                        Kb, Vb, Nd, E);
    attn_kernel<<<Nd, 128, 0, stream>>>(Q, Kb, Vb, order, offs, counts, agg);
    gemm_node_kernel<<<(Nd + 63) / 64, 256, 0, stream>>>(agg, h, wout, bout, rst, Nd, 8, 1);
    ln_kernel<<<(Nd + 3) / 4, 256, 0, stream>>>(rst, gamma, beta, (float*)d_out, Nd);
}

// Round 2
// 1150.865 us; speedup vs baseline: 1.1414x; 1.0495x over previous
//
#include <hip/hip_runtime.h>
#include <hip/hip_bf16.h>
#include <cstdint>
#include <cstddef>

#define LN_EPS 1e-5f

typedef __attribute__((ext_vector_type(8))) short short8;   // 8 bf16 = 4 VGPRs
typedef __attribute__((ext_vector_type(4))) float f32x4;    // MFMA accumulator

static __device__ __forceinline__ unsigned short f2bf(float x) {
    union { float f; unsigned u; } v; v.f = x;
    unsigned r = v.u + 0x7FFFu + ((v.u >> 16) & 1u);   // round-to-nearest-even
    return (unsigned short)(r >> 16);
}
static __device__ __forceinline__ float bf2f(unsigned short b) {
    union { unsigned u; float f; } v; v.u = ((unsigned)b) << 16;
    return v.f;
}
// two fp32 -> packed bf16x2 (compiler emits v_cvt_pk_bf16_f32 on gfx950)
static __device__ __forceinline__ unsigned cvt2(float lo, float hi) {
    float2 p; p.x = lo; p.y = hi;
    __hip_bfloat162 h = __float22bfloat162_rn(p);
    unsigned u; __builtin_memcpy(&u, &h, 4); return u;
}

// ---------------- weight prep: fp32 -> bf16, fold zero_time_feat into q-bias ----
__global__ void prep_kernel(const float* __restrict__ Wq, const float* __restrict__ bq,
                            const float* __restrict__ Wk, const float* __restrict__ Wv,
                            const float* __restrict__ Wout, const float* __restrict__ tb,
                            unsigned short* __restrict__ wkv, unsigned short* __restrict__ wq,
                            unsigned short* __restrict__ wout, float* __restrict__ qbias) {
    int tid = blockIdx.x * blockDim.x + threadIdx.x;
    if (tid < 256 * 384) {           // WKV: rows 0..127 = Wk, 128..255 = Wv  [256][384]
        int o = tid / 384, k = tid % 384;
        float w = (o < 128) ? Wk[o * 384 + k] : Wv[(o - 128) * 384 + k];
        wkv[tid] = f2bf(w);
    }
    if (tid < 128 * 128) {           // Wq first 128 input cols  [128][128]
        int o = tid / 128, i = tid % 128;
        wq[tid] = f2bf(Wq[o * 256 + i]);
    }
    if (tid < 128 * 256) {           // Wout  [128][256]
        wout[tid] = f2bf(Wout[tid]);
    }
    if (tid < 128) {                 // qbias[o] = bq[o] + sum_t cos(tb[t]) * Wq[o][128+t]
        float s = bq[tid];
        for (int t = 0; t < 128; ++t) s += cosf(tb[t]) * Wq[tid * 256 + 128 + t];
        qbias[tid] = s;
    }
}

// ---------------- fused K/V GEMM v3 --------------------------------------------
// tile 128 edges x 256 outputs, 512 thr (8 waves, 2M x 4N), K=384.
// K-chunks 0..3 (h,f cols): fp32 via global_load_lds (linear LDS dest,
//   inverse-swizzled global source), swizzle (row&15)<<4 -> conflict-free
//   ds_read_b128 at fp32 row stride 256B.
// K-chunks 4..5 (time feat): computed per-lane in registers, no LDS.
// Epilogue: acc -> LDS [128 edge][256 ch] bf16 image (16B-XOR swizzled),
//   then streamed out as contiguous 256B rows -> full-cache-line stores.
__launch_bounds__(512, 4)
__global__ void gemm_kv_kernel(const float* __restrict__ h, const float* __restrict__ f,
                               const float* __restrict__ dt, const float* __restrict__ freq,
                               const float* __restrict__ tb,
                               const unsigned short* __restrict__ wkv,
                               const float* __restrict__ bk, const float* __restrict__ bv,
                               unsigned short* __restrict__ Kb, unsigned short* __restrict__ Vb,
                               int Nd, int E) {
    __shared__ __align__(1024) float ldsA[2][8192];      // 2 x 32KB: [128 rows][64 f32]
    const int tid = threadIdx.x;
    const int w  = tid >> 6, l = tid & 63, ln = l & 15, lq = l >> 4;
    const int wm = w >> 2, wn = w & 3;                   // wave grid 2M x 4N
    const long e_base = (long)blockIdx.x * 128;

    auto stage = [&](int c, int buf) {                   // one 64-col fp32 K-chunk
        #pragma unroll
        for (int i = 0; i < 4; ++i) {
            int inst = w * 4 + i;                        // 32 x 1KB instrs across 8 waves
            int a    = inst * 1024 + l * 16;             // linear byte offset in 32KB tile
            int row  = a >> 8;
            int colb = (a & 255) ^ ((row & 15) << 4);    // inverse-swizzled source col
            long er  = e_base + row; if (er >= E) er = E - 1;
            const float* g = (c < 2) ? h + ((long)Nd + er) * 128 + c * 64 + (colb >> 2)
                                     : f + er * 128 + (c - 2) * 64 + (colb >> 2);
            __builtin_amdgcn_global_load_lds(
                (const __attribute__((address_space(1))) void*)g,
                (__attribute__((address_space(3))) void*)&ldsA[buf][inst * 256],
                16, 0, 0);
        }
    };

    stage(0, 0);
    f32x4 acc[4][4] = {};
    __syncthreads();

    int buf = 0;
    #pragma unroll
    for (int c = 0; c < 4; ++c) {
        // weight frags first (older than prefetch -> counted vmcnt wait)
        short8 wfr[2][4];
        #pragma unroll
        for (int ksl = 0; ksl < 2; ++ksl)
            #pragma unroll
            for (int nt = 0; nt < 4; ++nt) {
                int o = wn * 64 + nt * 16 + ln;
                wfr[ksl][nt] = *(const short8*)(wkv + o * 384 + c * 64 + ksl * 32 + lq * 8);
            }
        if (c < 3) stage(c + 1, buf ^ 1);                // prefetch next chunk
        #pragma unroll
        for (int ksl = 0; ksl < 2; ++ksl) {
            #pragma unroll
            for (int mt = 0; mt < 4; ++mt) {
                int row = wm * 64 + mt * 16 + ln;
                int swz = (row & 15) << 4;
                int c0  = ksl * 128 + lq * 32;           // byte col of 32B fragment
                const char* base = (const char*)&ldsA[buf][0] + row * 256;
                float4 x0 = *(const float4*)(base + ((c0     ) ^ swz));
                float4 x1 = *(const float4*)(base + ((c0 + 16) ^ swz));
                union { short8 s; unsigned u[4]; } v;
                v.u[0] = cvt2(x0.x, x0.y); v.u[1] = cvt2(x0.z, x0.w);
                v.u[2] = cvt2(x1.x, x1.y); v.u[3] = cvt2(x1.z, x1.w);
                #pragma unroll
                for (int nt = 0; nt < 4; ++nt)
                    acc[mt][nt] = __builtin_amdgcn_mfma_f32_16x16x32_bf16(
                        wfr[ksl][nt], v.s, acc[mt][nt], 0, 0, 0);
            }
        }
        __syncthreads();
        buf ^= 1;
    }

    // ---- time-feature K-chunks (t = 0..127), fully in-register ----
    float dval[4];
    #pragma unroll
    for (int mt = 0; mt < 4; ++mt) {
        long e = e_base + wm * 64 + mt * 16 + ln;
        if (e >= E) e = E - 1;
        dval[mt] = dt[e];
    }
    #pragma unroll
    for (int ks = 0; ks < 4; ++ks) {
        int t0 = ks * 32 + lq * 8;
        short8 wfr[4];
        #pragma unroll
        for (int nt = 0; nt < 4; ++nt) {
            int o = wn * 64 + nt * 16 + ln;
            wfr[nt] = *(const short8*)(wkv + o * 384 + 256 + ks * 32 + lq * 8);
        }
        float4 f0 = *(const float4*)(freq + t0);
        float4 f1 = *(const float4*)(freq + t0 + 4);
        float4 b0 = *(const float4*)(tb + t0);
        float4 b1 = *(const float4*)(tb + t0 + 4);
        #pragma unroll
        for (int mt = 0; mt < 4; ++mt) {
            float d = dval[mt];
            union { short8 s; unsigned u[4]; } v;
            v.u[0] = cvt2(__cosf(fmaf(d, f0.x, b0.x)), __cosf(fmaf(d, f0.y, b0.y)));
            v.u[1] = cvt2(__cosf(fmaf(d, f0.z, b0.z)), __cosf(fmaf(d, f0.w, b0.w)));
            v.u[2] = cvt2(__cosf(fmaf(d, f1.x, b1.x)), __cosf(fmaf(d, f1.y, b1.y)));
            v.u[3] = cvt2(__cosf(fmaf(d, f1.z, b1.z)), __cosf(fmaf(d, f1.w, b1.w)));
            #pragma unroll
            for (int nt = 0; nt < 4; ++nt)
                acc[mt][nt] = __builtin_amdgcn_mfma_f32_16x16x32_bf16(
                    wfr[nt], v.s, acc[mt][nt], 0, 0, 0);
        }
    }

    // ---- epilogue: acc -> LDS bf16 image [128 edge][512B], swizzled 16B slots --
    unsigned short* lout = (unsigned short*)&ldsA[0][0];   // 64KB reuse
    #pragma unroll
    for (int nt = 0; nt < 4; ++nt) {
        int o0 = wn * 64 + nt * 16 + lq * 4;             // K/V side uniform per wave
        const float* bsrc = (o0 < 128) ? (bk + o0) : (bv + (o0 - 128));
        float4 b4 = *(const float4*)bsrc;
        #pragma unroll
        for (int mt = 0; mt < 4; ++mt) {
            int el = wm * 64 + mt * 16 + ln;             // local edge 0..127
            f32x4 a = acc[mt][nt];
            uint2 u;
            u.x = cvt2(a[0] + b4.x, a[1] + b4.y);
            u.y = cvt2(a[2] + b4.z, a[3] + b4.w);
            int byte = (o0 * 2) ^ ((el & 7) << 4);       // self-inverse 16B-slot XOR
            *(uint2*)((char*)lout + el * 512 + byte) = u;
        }
    }
    __syncthreads();
    // stream out: contiguous 256B rows, uint4 per lane -> full cache lines
    #pragma unroll
    for (int p = 0; p < 8; ++p) {
        int g   = p * 512 + tid;                         // 0..4095
        int el  = g >> 5;                                // 32 x 16B chunks per edge
        int c16 = g & 31;
        int byte = (c16 * 16) ^ ((el & 7) << 4);
        uint4 dta = *(const uint4*)((const char*)lout + el * 512 + byte);
        long e = e_base + el;
        if (e < E) {
            if (c16 < 16) *(uint4*)(Kb + e * 128 + c16 * 8) = dta;
            else          *(uint4*)(Vb + e * 128 + (c16 - 16) * 8) = dta;
        }
    }
}

// ---------------- node GEMM: out[M][128] = [src0 | src1] @ W^T + bias (opt relu) ---
// ksteps = Kd/32 (4 for Q, 8 for Wout). block 256 thr, tile 64 rows x 128 cols.
// MFMA operands swapped -> float4 epilogue stores (64B/row per instr, full lines).
__launch_bounds__(256)
__global__ void gemm_node_kernel(const float* __restrict__ src0, const float* __restrict__ src1,
                                 const unsigned short* __restrict__ W, const float* __restrict__ bias,
                                 float* __restrict__ out, int M, int ksteps, int do_relu) {
    __shared__ unsigned short ldsA[4 * 8 * 64 * 8];      // up to Kd=256
    const int tid = threadIdx.x;
    const long m_base = (long)blockIdx.x * 64;
    const int Kd = ksteps * 32;
    const int g4 = Kd / 4;

    for (int g = tid; g < 64 * g4; g += 256) {
        int r  = g / g4;
        int c4 = (g % g4) * 4;
        long m = m_base + r; if (m >= M) m = M - 1;
        float4 x = (c4 < 128) ? *(const float4*)(src0 + m * 128 + c4)
                              : *(const float4*)(src1 + m * 128 + (c4 - 128));
        int lane = (r & 15) | (((c4 >> 3) & 3) << 4);
        int base = (((r >> 4) * ksteps + (c4 >> 5)) * 64 + lane) * 8 + (c4 & 7);
        *(unsigned*)&ldsA[base]     = cvt2(x.x, x.y);
        *(unsigned*)&ldsA[base + 2] = cvt2(x.z, x.w);
    }
    __syncthreads();

    const int w = tid >> 6, l = tid & 63, ln = l & 15, lq = l >> 4;
    f32x4 acc[4][2] = {};
    for (int ks = 0; ks < ksteps; ++ks) {
        short8 bfr[2];
        #pragma unroll
        for (int nt = 0; nt < 2; ++nt) {
            int row = w * 32 + nt * 16 + ln;             // W stored [N][K] row-major
            bfr[nt] = *(const short8*)(W + row * Kd + ks * 32 + lq * 8);
        }
        #pragma unroll
        for (int mt = 0; mt < 4; ++mt) {
            short8 afr = *(const short8*)&ldsA[((mt * ksteps + ks) * 64 + l) * 8];
            #pragma unroll
            for (int nt = 0; nt < 2; ++nt)
                acc[mt][nt] = __builtin_amdgcn_mfma_f32_16x16x32_bf16(
                    bfr[nt], afr, acc[mt][nt], 0, 0, 0);
        }
    }
    #pragma unroll
    for (int nt = 0; nt < 2; ++nt) {
        int o0 = w * 32 + nt * 16 + lq * 4;
        float4 b4 = *(const float4*)(bias + o0);
        #pragma unroll
        for (int mt = 0; mt < 4; ++mt) {
            long m = m_base + mt * 16 + ln;
            if (m >= M) continue;
            f32x4 a = acc[mt][nt];
            float4 o;
            o.x = a[0] + b4.x; o.y = a[1] + b4.y;
            o.z = a[2] + b4.z; o.w = a[3] + b4.w;
            if (do_relu) {
                o.x = fmaxf(o.x, 0.f); o.y = fmaxf(o.y, 0.f);
                o.z = fmaxf(o.z, 0.f); o.w = fmaxf(o.w, 0.f);
            }
            *(float4*)(out + m * 128 + o0) = o;
        }
    }
}

// ---------------- counting sort of edges by dst ----------------
__global__ void hist_kernel(const int* __restrict__ dst, int* __restrict__ counts, int E) {
    int e = blockIdx.x * blockDim.x + threadIdx.x;
    if (e < E) atomicAdd(&counts[dst[e]], 1);
}

__global__ void scan_kernel(const int* __restrict__ counts, int* __restrict__ offsets,
                            int* __restrict__ cursor, int Nd) {
    __shared__ int sdata[1024];
    int t = threadIdx.x;
    int C = (Nd + 1023) / 1024;
    int b0 = t * C;
    int s = 0;
    for (int i = 0; i < C; ++i) { int idx = b0 + i; if (idx < Nd) s += counts[idx]; }
    sdata[t] = s;
    __syncthreads();
    for (int off = 1; off < 1024; off <<= 1) {
        int v = (t >= off) ? sdata[t - off] : 0;
        __syncthreads();
        sdata[t] += v;
        __syncthreads();
    }
    int run = sdata[t] - s;                              // exclusive prefix of this chunk
    for (int i = 0; i < C; ++i) {
        int idx = b0 + i;
        if (idx < Nd) { offsets[idx] = run; cursor[idx] = run; run += counts[idx]; }
    }
}

__global__ void scatter_kernel(const int* __restrict__ dst, int* __restrict__ cursor,
                               int* __restrict__ order, int E) {
    int e = blockIdx.x * blockDim.x + threadIdx.x;
    if (e < E) { int pos = atomicAdd(&cursor[dst[e]], 1); order[pos] = e; }
}

// ---------------- attention: one WAVE per dst node, 2 channels per lane ----------
// packed uint K/V loads (4B/lane), width-8 shuffle dot, online softmax.
__launch_bounds__(256)
__global__ void attn_kernel(const float* __restrict__ Q, const unsigned short* __restrict__ Kb,
                            const unsigned short* __restrict__ Vb,
                            const int* __restrict__ order, const int* __restrict__ offsets,
                            const int* __restrict__ counts, float* __restrict__ agg, int Nd) {
    const int wv = threadIdx.x >> 6;
    const int l  = threadIdx.x & 63;
    const long d = (long)blockIdx.x * 4 + wv;
    if (d >= Nd) return;
    const int beg = offsets[d];
    const int n   = counts[d];
    float2 q = *(const float2*)(Q + d * 128 + l * 2);

    float m = -3.0e38f, lsum = 0.f;
    float2 acc; acc.x = 0.f; acc.y = 0.f;
    unsigned kk = 0, vv = 0;
    if (n > 0) {
        long e0 = order[beg];
        kk = *(const unsigned*)(Kb + e0 * 128 + l * 2);
        vv = *(const unsigned*)(Vb + e0 * 128 + l * 2);
    }
    for (int i = 0; i < n; ++i) {
        unsigned ck = kk, cv = vv;
        if (i + 1 < n) {                                 // prefetch next edge's rows
            long e2 = order[beg + i + 1];
            kk = *(const unsigned*)(Kb + e2 * 128 + l * 2);
            vv = *(const unsigned*)(Vb + e2 * 128 + l * 2);
        }
        float k0 = bf2f((unsigned short)(ck & 0xFFFFu));
        float k1 = bf2f((unsigned short)(ck >> 16));
        float p = q.x * k0 + q.y * k1;
        p += __shfl_xor(p, 1, 8);
        p += __shfl_xor(p, 2, 8);
        p += __shfl_xor(p, 4, 8);                        // per-head dot (16ch / 2 per lane)
        float logit = (p > 0.f) ? p : 0.2f * p;          // leaky_relu 0.2
        float mn = fmaxf(m, logit);
        float sc = __expf(m - mn);
        float pe = __expf(logit - mn);
        float v0 = bf2f((unsigned short)(cv & 0xFFFFu));
        float v1 = bf2f((unsigned short)(cv >> 16));
        lsum  = lsum  * sc + pe;
        acc.x = acc.x * sc + pe * v0;
        acc.y = acc.y * sc + pe * v1;
        m = mn;
    }
    float inv = (n > 0) ? 1.f / lsum : 0.f;
    float2 o; o.x = acc.x * inv; o.y = acc.y * inv;
    *(float2*)(agg + d * 128 + l * 2) = o;
}

// ---------------- layernorm (one wave per row) ----------------
__launch_bounds__(256)
__global__ void ln_kernel(const float* __restrict__ rst, const float* __restrict__ gamma,
                          const float* __restrict__ beta, float* __restrict__ out, int Nd) {
    int wave = threadIdx.x >> 6;
    int lane = threadIdx.x & 63;
    long row = (long)blockIdx.x * 4 + wave;
    if (row >= Nd) return;
    float x0 = rst[row * 128 + lane];
    float x1 = rst[row * 128 + 64 + lane];
    float s = x0 + x1, sq = x0 * x0 + x1 * x1;
    #pragma unroll
    for (int off = 32; off >= 1; off >>= 1) {
        s  += __shfl_xor(s, off, 64);
        sq += __shfl_xor(sq, off, 64);
    }
    float mean = s * (1.f / 128.f);
    float var  = sq * (1.f / 128.f) - mean * mean;
    float rstd = rsqrtf(var + LN_EPS);
    out[row * 128 + lane]      = (x0 - mean) * rstd * gamma[lane]      + beta[lane];
    out[row * 128 + 64 + lane] = (x1 - mean) * rstd * gamma[lane + 64] + beta[lane + 64];
}

// ---------------- host ----------------
extern "C" void kernel_launch(void* const* d_in, const int* in_sizes, int n_in,
                              void* d_out, int out_size, void* d_ws, size_t ws_size,
                              hipStream_t stream) {
    const float* h    = (const float*)d_in[0];
    const float* f    = (const float*)d_in[1];
    const float* dt   = (const float*)d_in[2];
    const int*   dst  = (const int*)d_in[3];
    const float* freq = (const float*)d_in[4];
    const float* tb   = (const float*)d_in[5];
    const float* Wq   = (const float*)d_in[6];
    const float* bq   = (const float*)d_in[7];
    const float* Wk   = (const float*)d_in[8];
    const float* bk   = (const float*)d_in[9];
    const float* Wv   = (const float*)d_in[10];
    const float* bv   = (const float*)d_in[11];
    const float* Wout = (const float*)d_in[12];
    const float* bout = (const float*)d_in[13];
    const float* gamma= (const float*)d_in[14];
    const float* beta = (const float*)d_in[15];

    const int E  = in_sizes[2];
    const int Nd = in_sizes[0] / 128 - E;

    char* ws = (char*)d_ws;
    size_t off = 0;
    auto alloc = [&](size_t b) {
        off = (off + 255) & ~(size_t)255;
        char* p = ws + off; off += b; return p;
    };
    unsigned short* wkv   = (unsigned short*)alloc(256 * 384 * 2);
    unsigned short* wq    = (unsigned short*)alloc(128 * 128 * 2);
    unsigned short* wout  = (unsigned short*)alloc(128 * 256 * 2);
    float*          qbias = (float*)alloc(128 * 4);
    float*          Q     = (float*)alloc((size_t)Nd * 128 * 4);
    unsigned short* Kb    = (unsigned short*)alloc((size_t)E * 128 * 2);
    unsigned short* Vb    = (unsigned short*)alloc((size_t)E * 128 * 2);
    float*          agg   = (float*)alloc((size_t)Nd * 128 * 4);
    int*            counts= (int*)alloc((size_t)Nd * 4);
    int*            offs  = (int*)alloc((size_t)Nd * 4);
    int*            cursor= (int*)alloc((size_t)Nd * 4);
    int*            order = (int*)alloc((size_t)E * 4);
    float*          rst   = (float*)Kb;   // alias: Kb dead after attention

    hipMemsetAsync(counts, 0, (size_t)Nd * 4, stream);
    prep_kernel<<<(256 * 384 + 255) / 256, 256, 0, stream>>>(Wq, bq, Wk, Wv, Wout, tb,
                                                             wkv, wq, wout, qbias);
    hist_kernel<<<(E + 255) / 256, 256, 0, stream>>>(dst, counts, E);
    scan_kernel<<<1, 1024, 0, stream>>>(counts, offs, cursor, Nd);
    scatter_kernel<<<(E + 255) / 256, 256, 0, stream>>>(dst, cursor, order, E);
    gemm_node_kernel<<<(Nd + 63) / 64, 256, 0, stream>>>(h, nullptr, wq, qbias, Q, Nd, 4, 0);
    gemm_kv_kernel<<<(E + 127) / 128, 512, 0, stream>>>(h, f, dt, freq, tb, wkv, bk, bv,
                                                        Kb, Vb, Nd, E);
    attn_kernel<<<(Nd + 3) / 4, 256, 0, stream>>>(Q, Kb, Vb, order, offs, counts, agg, Nd);
    gemm_node_kernel<<<(Nd + 63) / 64, 256, 0, stream>>>(agg, h, wout, bout, rst, Nd, 8, 1);
    ln_kernel<<<(Nd + 3) / 4, 256, 0, stream>>>(rst, gamma, beta, (float*)d_out, Nd);
}